// Round 8
// baseline (39.314 us; speedup 1.0000x reference)
//
#include <hip/hip_runtime.h>
#include <hip/hip_bf16.h>

#define D_IN  512
#define C_OUT 128
#define HW    16384   // 128*128 per batch
#define BM    128     // m-rows per block
#define BC    64      // channels per block (c-split)
#define BK    64
#define PAD   72      // 144B row stride -> 2-way LDS aliasing on b128 reads (free, m136)

typedef __attribute__((ext_vector_type(8))) short bf16x8;
typedef __attribute__((ext_vector_type(4))) float f32x4;

__device__ __forceinline__ ushort bf(float f) {
    // scalar cast -> compiler emits packed v_cvt_pk_bf16_f32 (RNE), per m240
    return __builtin_bit_cast(ushort, __float2bfloat16(f));
}

__global__ __launch_bounds__(256, 4) void cwp_gemm(
    const float* __restrict__ x, const float* __restrict__ W,
    const float* __restrict__ bias, float* __restrict__ out)
{
    __shared__ ushort Ws[BC * PAD];   //  9 KB  [c][k] bf16 (this block's 64 channels)
    __shared__ ushort Xs[BM * PAD];   // 18 KB  [m][k] bf16

    const int t    = threadIdx.x;
    const int lane = t & 63;
    const int wid  = t >> 6;     // 0..3
    const int wr   = wid >> 1;   // 0..1 : c-quarter (32 channels)
    const int wc   = wid & 1;    // 0..1 : m-half    (64 rows)
    const int q    = lane >> 4;  // 0..3
    const int lr   = lane & 15;

    // m-block-major ordering: blocks b and b+512 share m-range and land on
    // the same XCD (b%8), so the x re-read by the second c-half hits L2/L3.
    const int bid  = blockIdx.x;
    const int mb   = bid & 511;        // m-block
    const int ch   = bid >> 9;         // c-half
    const int m0   = mb * BM;
    const int cblk = ch * BC;
    const int bidx = m0 / HW;
    const int hw0  = m0 % HW;

    f32x4 acc[2][4];   // [ci (16c)][mt (16m)]
    #pragma unroll
    for (int i = 0; i < 2; ++i)
        #pragma unroll
        for (int j = 0; j < 4; ++j)
            acc[i][j] = (f32x4){0.f, 0.f, 0.f, 0.f};

    const int srow = t >> 4;  // 0..15 staging row base
    const int scol = t & 15;  // f32x4 column within BK

    for (int kt = 0; kt < D_IN; kt += BK) {
        // ---- staging loads: 4 f32x4 of W (64 c-rows) + 8 f32x4 of x (128 m-rows) ----
        f32x4 wv[4], xv[8];
        #pragma unroll
        for (int p = 0; p < 4; ++p) {
            const int r = p * 16 + srow;
            wv[p] = *reinterpret_cast<const f32x4*>(&W[(cblk + r) * D_IN + kt + scol * 4]);
        }
        #pragma unroll
        for (int p = 0; p < 8; ++p) {
            const int r = p * 16 + srow;
            xv[p] = *reinterpret_cast<const f32x4*>(&x[(size_t)(m0 + r) * D_IN + kt + scol * 4]);
        }
        __syncthreads();  // previous tile's compute done before LDS overwrite
        #pragma unroll
        for (int p = 0; p < 4; ++p) {
            const int r = p * 16 + srow;
            *reinterpret_cast<ushort4*>(&Ws[r * PAD + scol * 4]) =
                make_ushort4(bf(wv[p][0]), bf(wv[p][1]), bf(wv[p][2]), bf(wv[p][3]));
        }
        #pragma unroll
        for (int p = 0; p < 8; ++p) {
            const int r = p * 16 + srow;
            *reinterpret_cast<ushort4*>(&Xs[r * PAD + scol * 4]) =
                make_ushort4(bf(xv[p][0]), bf(xv[p][1]), bf(xv[p][2]), bf(xv[p][3]));
        }
        __syncthreads();

        // ---- compute: 2 k-subs x 8 MFMA per wave ----
        #pragma unroll
        for (int ks = 0; ks < 2; ++ks) {
            bf16x8 af[2], bfv[4];
            #pragma unroll
            for (int i = 0; i < 2; ++i)
                af[i]  = *reinterpret_cast<const bf16x8*>(&Ws[(wr*32 + i*16 + lr) * PAD + ks*32 + q*8]);
            #pragma unroll
            for (int j = 0; j < 4; ++j)
                bfv[j] = *reinterpret_cast<const bf16x8*>(&Xs[(wc*64 + j*16 + lr) * PAD + ks*32 + q*8]);
            #pragma unroll
            for (int i = 0; i < 2; ++i)
                #pragma unroll
                for (int j = 0; j < 4; ++j)
                    acc[i][j] = __builtin_amdgcn_mfma_f32_16x16x32_bf16(af[i], bfv[j], acc[i][j], 0, 0, 0);
        }
    }

    // ---- epilogue: D row = c-local (q*4+jj), col = m-local (lane&15) ----
    float* outb = out + (size_t)bidx * C_OUT * HW;
    #pragma unroll
    for (int i = 0; i < 2; ++i) {
        const int c0 = cblk + wr*32 + i*16 + q*4;
        #pragma unroll
        for (int j = 0; j < 4; ++j) {
            const int m = hw0 + wc*64 + j*16 + lr;
            #pragma unroll
            for (int jj = 0; jj < 4; ++jj)
                outb[(size_t)(c0 + jj) * HW + m] = acc[i][j][jj] + bias[c0 + jj];
        }
    }
}

extern "C" void kernel_launch(void* const* d_in, const int* in_sizes, int n_in,
                              void* d_out, int out_size, void* d_ws, size_t ws_size,
                              hipStream_t stream) {
    const float* x    = (const float*)d_in[0];
    const float* W    = (const float*)d_in[1];
    const float* b    = (const float*)d_in[2];
    float* out        = (float*)d_out;
    const int M = 4 * HW;              // 65536 rows
    dim3 grid((M / BM) * (C_OUT / BC));  // 512 m-blocks x 2 c-halves = 1024 -> 4/CU
    cwp_gemm<<<grid, 256, 0, stream>>>(x, W, b, out);
}

// Round 9
// 29.582 us; speedup vs baseline: 1.3290x; 1.3290x over previous
//
#include <hip/hip_runtime.h>
#include <hip/hip_bf16.h>

#define D_IN  512
#define C_OUT 128
#define HW    16384   // 128*128 per batch
#define BM    128
#define BK    64
#define PAD   72      // 144B row stride -> 2-way LDS aliasing on b128 reads (free, m136)
#define NKT   (D_IN / BK)   // 8 K-steps

typedef __attribute__((ext_vector_type(8))) short bf16x8;
typedef __attribute__((ext_vector_type(4))) float f32x4;

__device__ __forceinline__ ushort bf(float f) {
    // scalar cast -> compiler emits packed v_cvt_pk_bf16_f32 (RNE), per m240
    return __builtin_bit_cast(ushort, __float2bfloat16(f));
}

__global__ __launch_bounds__(256) void cwp_gemm(
    const float* __restrict__ x, const float* __restrict__ W,
    const float* __restrict__ bias, float* __restrict__ out)
{
    __shared__ ushort Ws[C_OUT * PAD];   // W tile  [c][k], bf16
    __shared__ ushort Xs[BM * PAD];      // x tile  [m][k], bf16

    const int t    = threadIdx.x;
    const int lane = t & 63;
    const int wid  = t >> 6;     // 0..3
    const int wr   = wid >> 1;   // c-half of block tile
    const int wc   = wid & 1;    // m-half of block tile
    const int q    = lane >> 4;  // 0..3
    const int lr   = lane & 15;

    const int m0   = blockIdx.x * BM;
    const int bidx = m0 / HW;
    const int hw0  = m0 % HW;

    f32x4 acc[4][4];
    #pragma unroll
    for (int i = 0; i < 4; ++i)
        #pragma unroll
        for (int j = 0; j < 4; ++j)
            acc[i][j] = (f32x4){0.f, 0.f, 0.f, 0.f};

    const int srow = t >> 4;  // 0..15: row-within-pass
    const int scol = t & 15;  // f32x4 column within BK

    f32x4 wv[8], xv[8];

    // ---- prologue: issue loads for tile 0 ----
    #pragma unroll
    for (int p = 0; p < 8; ++p) {
        const int r = p * 16 + srow;
        wv[p] = *reinterpret_cast<const f32x4*>(&W[r * D_IN + scol * 4]);
        xv[p] = *reinterpret_cast<const f32x4*>(&x[(size_t)(m0 + r) * D_IN + scol * 4]);
    }

    for (int k = 0; k < NKT; ++k) {
        // sync#1: previous compute's LDS reads done; drains loads(k) —
        // whose latency was hidden under compute(k-1).
        __syncthreads();

        // ---- cvt + LDS write tile k ----
        #pragma unroll
        for (int p = 0; p < 8; ++p) {
            const int r = p * 16 + srow;
            *reinterpret_cast<ushort4*>(&Ws[r * PAD + scol * 4]) =
                make_ushort4(bf(wv[p][0]), bf(wv[p][1]), bf(wv[p][2]), bf(wv[p][3]));
            *reinterpret_cast<ushort4*>(&Xs[r * PAD + scol * 4]) =
                make_ushort4(bf(xv[p][0]), bf(xv[p][1]), bf(xv[p][2]), bf(xv[p][3]));
        }
        __syncthreads();  // sync#2: tile k visible

        // ---- issue loads(k+1): in flight across the whole compute phase ----
        if (k + 1 < NKT) {
            const int kt = (k + 1) * BK;
            #pragma unroll
            for (int p = 0; p < 8; ++p) {
                const int r = p * 16 + srow;
                wv[p] = *reinterpret_cast<const f32x4*>(&W[r * D_IN + kt + scol * 4]);
                xv[p] = *reinterpret_cast<const f32x4*>(&x[(size_t)(m0 + r) * D_IN + kt + scol * 4]);
            }
        }

        // ---- compute tile k: 2 k-subs x 16 MFMA per wave ----
        #pragma unroll
        for (int ks = 0; ks < 2; ++ks) {
            bf16x8 af[4], bfv[4];
            #pragma unroll
            for (int i = 0; i < 4; ++i) {
                af[i]  = *reinterpret_cast<const bf16x8*>(&Ws[(wr*64 + i*16 + lr) * PAD + ks*32 + q*8]);
                bfv[i] = *reinterpret_cast<const bf16x8*>(&Xs[(wc*64 + i*16 + lr) * PAD + ks*32 + q*8]);
            }
            #pragma unroll
            for (int i = 0; i < 4; ++i)
                #pragma unroll
                for (int j = 0; j < 4; ++j)
                    acc[i][j] = __builtin_amdgcn_mfma_f32_16x16x32_bf16(af[i], bfv[j], acc[i][j], 0, 0, 0);
        }
    }

    // ---- epilogue: D[row=c-local][col=m-local]; row=(lane>>4)*4+jj, col=lane&15 ----
    float bv[4][4];
    #pragma unroll
    for (int i = 0; i < 4; ++i)
        #pragma unroll
        for (int jj = 0; jj < 4; ++jj)
            bv[i][jj] = bias[wr*64 + i*16 + q*4 + jj];

    float* outb = out + (size_t)bidx * C_OUT * HW;
    #pragma unroll
    for (int i = 0; i < 4; ++i) {
        const int c0 = wr*64 + i*16 + q*4;
        #pragma unroll
        for (int j = 0; j < 4; ++j) {
            const int m = hw0 + wc*64 + j*16 + lr;
            #pragma unroll
            for (int jj = 0; jj < 4; ++jj)
                outb[(size_t)(c0 + jj) * HW + m] = acc[i][j][jj] + bv[i][jj];
        }
    }
}

extern "C" void kernel_launch(void* const* d_in, const int* in_sizes, int n_in,
                              void* d_out, int out_size, void* d_ws, size_t ws_size,
                              hipStream_t stream) {
    const float* x    = (const float*)d_in[0];
    const float* W    = (const float*)d_in[1];
    const float* b    = (const float*)d_in[2];
    float* out        = (float*)d_out;
    const int M = 4 * HW;              // 65536 rows
    dim3 grid(M / BM);                 // 512 blocks, 2 per CU
    cwp_gemm<<<grid, 256, 0, stream>>>(x, W, b, out);
}